// Round 10
// baseline (402.174 us; speedup 1.0000x reference)
//
#include <hip/hip_runtime.h>

typedef __attribute__((ext_vector_type(8))) short bf16x8;   // 8 bf16 = 4 VGPRs
typedef __attribute__((ext_vector_type(4))) float f32x4;    // MFMA C/D

__device__ __forceinline__ float bf2f(unsigned short u){
    unsigned int v = ((unsigned int)u) << 16;
    return __builtin_bit_cast(float, v);
}
__device__ __forceinline__ unsigned short f2bf(float f){
    unsigned int u = __builtin_bit_cast(unsigned int, f);
    u += 0x7FFFu + ((u >> 16) & 1u);   // RTNE (no NaN inputs here)
    return (unsigned short)(u >> 16);
}
// HW packed f32->bf16 RTNE (verified correct rounds 3/6/8)
__device__ __forceinline__ unsigned int cvt_pk_bf16(float lo, float hi){
    unsigned int r;
    asm("v_cvt_pk_bf16_f32 %0, %1, %2" : "=v"(r) : "v"(lo), "v"(hi));
    return r;
}
__device__ __forceinline__ unsigned int mulpack(unsigned int u, float xf){
    float flo = __builtin_bit_cast(float, u << 16);
    float fhi = __builtin_bit_cast(float, u & 0xffff0000u);
    return cvt_pk_bf16(xf * flo, xf * fhi);
}

// ---- prep: W (K x 256) fp32 -> Wt (256 x K) bf16, LDS-tiled transpose ----
__global__ void prep_wt(const float* __restrict__ W, unsigned short* __restrict__ Wt, int K){
    __shared__ float tile[64][65];
    const int k0 = blockIdx.x * 64;
    const int j0 = blockIdx.y * 64;
    const int t  = threadIdx.x;              // 256
    #pragma unroll
    for (int it = 0; it < 16; it++){
        int idx = it * 256 + t;
        int kr = idx >> 6, jc = idx & 63;
        tile[kr][jc] = W[(size_t)(k0 + kr) * 256 + j0 + jc];
    }
    __syncthreads();
    #pragma unroll
    for (int it = 0; it < 2; it++){
        int idx = it * 256 + t;
        int jr = idx >> 3, kc = (idx & 7) << 3;
        uint4 tv;
        unsigned short* ts = (unsigned short*)&tv;
        #pragma unroll
        for (int q = 0; q < 8; q++)
            ts[q] = f2bf(tile[kc + q][jr]);
        *(uint4*)(Wt + (size_t)(j0 + jr) * K + k0 + kc) = tv;
    }
}

// ---- prep: x (b,m,d) fp32 -> Xt[b][d][m] bf16 ----
__global__ void prep_x(const float* __restrict__ x, unsigned short* __restrict__ Xt){
    int b = blockIdx.x;
    int t = threadIdx.x;
    #pragma unroll
    for (int it = 0; it < 8; it++){
        int o = it * 256 + t;          // o = d*32 + m
        int d = o >> 5, m = o & 31;
        Xt[(size_t)b * 2048 + o] = f2bf(x[(size_t)b * 2048 + m * 64 + d]);
    }
}

__global__ void init_out(float* __restrict__ out, const float* __restrict__ fcb){
    int i = blockIdx.x * 256 + threadIdx.x;
    if (i < 1024) out[i] = fcb[0];
}

// ---- fused CIN stage: cooperative per-m Z-tile + pure GEMM, jt=4 ----
// 256 threads = 4 waves = 4 j-groups (j64 each, jt=0..3), c = 128 shared.
// Per m: Zm[c][n] = x[c][m]*h[c][n] built cooperatively (thread owns row
// c=t&127 -> conflict-free 8-lane bank residues (c+j)%8); then SB kt of pure
// MFMA, acc C-chained over all kt (AGPR). Single-buffered Zm, 2 barriers/m;
// LDS 79872 B -> 2 blocks/CU co-resident: block B covers block A's stalls.
// LDS-inst : MFMA cycle ratio ~1.08 (vs 1.8 at jt=2). A(m+1) loaded in the
// build window. Regs: acc 128 AGPR + A 64 + Bf 32 + misc ~ 240 -> 2 w/SIMD.
template<int NN, int KTOT, int JX, bool HAS_HOUT>
__global__ __launch_bounds__(256, 2) void cin_stage(
    const unsigned short* __restrict__ Xt,
    const unsigned short* __restrict__ Hin,
    const unsigned short* __restrict__ Wt,
    const float* __restrict__ bias,
    const float* __restrict__ fcW,      // pre-offset for this layer
    unsigned short* __restrict__ Hout,  // [b][d][n] bf16, n in [0,128); null if !HAS_HOUT
    float* __restrict__ out)
{
    constexpr int SB  = NN / 32;                 // kt per m
    constexpr int XS  = 40;                      // Xl row stride (shorts)
    constexpr int ZS  = (NN == 32) ? 40 : 136;   // Hl / Zm row stride (shorts)
    constexpr int XLSZ = 128 * XS;               // 5120 shorts
    constexpr int HLSZ = (NN == 32) ? 0 : 128 * ZS;
    constexpr int ZMSZ = 128 * ZS;
    constexpr int NEED = XLSZ + HLSZ + ZMSZ;
    constexpr int SMSZ = NEED > 17408 ? NEED : 17408;   // Yl overlay: 128*136

    __shared__ unsigned short smem[SMSZ];
    unsigned short* const Xl = smem;
    unsigned short* const Hl = (NN == 32) ? smem : (smem + XLSZ);   // h == x for stage 0
    unsigned short* const Zm = smem + XLSZ + HLSZ;
    unsigned short* const Yl = smem;             // epilogue overlay [n:128][c pad 136]

    const int t    = threadIdx.x;
    const int lane = t & 63;
    const int w    = t >> 6;        // 0..3 : j in [64w, 64w+64)
    const int li   = lane & 15;
    const int lq   = lane >> 4;
    const int bpair = blockIdx.x;

    // ---- one-time staging: x -> Xl row-major; h -> Hl row-major ----
    {
        const int c  = t >> 1;                  // 0..127
        const int b  = bpair * 2 + (c >> 6);
        const int d  = c & 63;
        const int half = t & 1;
        const int mh = half << 4;               // 16 shorts per thread
        const uint4* xsrc = (const uint4*)(Xt + ((size_t)b << 11) + (d << 5) + mh);
        uint4 x0 = xsrc[0], x1 = xsrc[1];
        *(uint4*)(Xl + c * XS + mh)     = x0;
        *(uint4*)(Xl + c * XS + mh + 8) = x1;
        if (NN == 128){
            const int nh = half << 6;           // 64 shorts per thread
            const uint4* hsrc = (const uint4*)(Hin + (size_t)((b << 6) + d) * 128 + nh);
            #pragma unroll
            for (int q = 0; q < 8; q++){
                uint4 hv = hsrc[q];
                *(uint4*)(Hl + c * ZS + nh + q * 8) = hv;
            }
        }
    }

    // cooperative Zm build: thread owns row c = t&127, chunk-half bh = t>>7.
    // 8-lane groups span 8 consecutive rows -> bank residues (c+j)%8 distinct.
    const int bc = t & 127;
    const int bh = t >> 7;                      // 0..1
    constexpr int CPT = (NN == 128) ? 8 : 2;    // 16B chunks per thread
    auto build = [&](int m){
        float xf = bf2f(Xl[bc * XS + m]);
        #pragma unroll
        for (int j = 0; j < CPT; j++){
            int off = (bh * CPT + j) << 3;      // shorts
            uint4 hv = *(const uint4*)(Hl + bc * ZS + off);
            uint4 zv;
            zv.x = mulpack(hv.x, xf);
            zv.y = mulpack(hv.y, xf);
            zv.z = mulpack(hv.z, xf);
            zv.w = mulpack(hv.w, xf);
            *(uint4*)(Zm + bc * ZS + off) = zv;
        }
    };

    // A fragments: lane reads Wt[j = 64w + jt*16 + li][kt*32 + lq*8 .. +8)
    const unsigned short* wrow = Wt + (size_t)((w << 6) + li) * KTOT + (lq << 3);
    bf16x8 A[4][SB];
    auto aload = [&](int m){
        #pragma unroll
        for (int jt = 0; jt < 4; jt++)
            #pragma unroll
            for (int s = 0; s < SB; s++)
                A[jt][s] = *(const bf16x8*)(wrow + (size_t)jt * 16 * KTOT + (m * SB + s) * 32);
    };

    f32x4 acc[4][8];   // pure MFMA C-chain over all kt -> AGPRs
    #pragma unroll
    for (int jt = 0; jt < 4; jt++)
        #pragma unroll
        for (int ct = 0; ct < 8; ct++)
            acc[jt][ct] = (f32x4){0.f, 0.f, 0.f, 0.f};

    __syncthreads();                 // staging done
    build(0);
    aload(0);
    __syncthreads();                 // Zm(0) ready

    for (int m = 0; m < 32; m++){
        #pragma unroll
        for (int s = 0; s < SB; s++){
            bf16x8 Bf[8];
            #pragma unroll
            for (int ct = 0; ct < 8; ct++)
                Bf[ct] = *(const bf16x8*)(Zm + ((ct << 4) + li) * ZS + (s << 5) + (lq << 3));
            #pragma unroll
            for (int ct = 0; ct < 8; ct++)
                #pragma unroll
                for (int jt = 0; jt < 4; jt++)
                    acc[jt][ct] = __builtin_amdgcn_mfma_f32_16x16x32_bf16(
                        A[jt][s], Bf[ct], acc[jt][ct], 0, 0, 0);
        }
        __syncthreads();             // all readers done with Zm(m)
        if (m < 31){
            aload(m + 1);            // global (L2) loads land during build+barrier
            build(m + 1);
        }
        __syncthreads();             // Zm(m+1) ready
    }

    if (HAS_HOUT) __syncthreads();   // Yl overlays Xl/Hl (and Zm for NN=32)

    // epilogue: bias + relu; fc partial sums; stage h-half into Yl overlay
    float pfc0 = 0.f, pfc1 = 0.f;
    #pragma unroll
    for (int jt = 0; jt < 4; jt++){
        const int jb = (w << 6) + (jt << 4) + (lq << 2);
        float bv[4], fv[4];
        #pragma unroll
        for (int r = 0; r < 4; r++){
            int j = jb + r;
            bv[r] = bias[j];
            fv[r] = (j < JX) ? fcW[j] : 0.f;
        }
        #pragma unroll
        for (int ct = 0; ct < 8; ct++){
            f32x4 f = acc[jt][ct];
            int c = (ct << 4) + li;
            float ps = 0.f;
            #pragma unroll
            for (int r = 0; r < 4; r++){
                float y = f[r] + bv[r];
                y = y > 0.f ? y : 0.f;
                ps += fv[r] * y;
                if (HAS_HOUT){
                    int j = jb + r;
                    if (j >= 128)
                        Yl[(j - 128) * 136 + c] = f2bf(y);
                }
            }
            if (ct < 4) pfc0 += ps; else pfc1 += ps;
        }
    }
    #pragma unroll
    for (int off = 32; off; off >>= 1){
        pfc0 += __shfl_xor(pfc0, off, 64);
        pfc1 += __shfl_xor(pfc1, off, 64);
    }
    if (lane == 0){
        atomicAdd(out + bpair * 2 + 0, pfc0);
        atomicAdd(out + bpair * 2 + 1, pfc1);
    }

    if (HAS_HOUT){
        __syncthreads();
        // cooperative store: Hout[(bpair*128 + c)*128 + n] = Yl[n][c]
        const int c  = t >> 1;
        const int nh = (t & 1) << 6;           // 64 shorts per thread
        unsigned short* gdst = Hout + (size_t)(bpair * 128 + c) * 128 + nh;
        #pragma unroll
        for (int i8 = 0; i8 < 8; i8++){
            uint4 tv;
            unsigned short* tmp2 = (unsigned short*)&tv;
            #pragma unroll
            for (int q = 0; q < 8; q++)
                tmp2[q] = Yl[(nh + i8 * 8 + q) * 136 + c];
            *(uint4*)(gdst + i8 * 8) = tv;
        }
    }
}

extern "C" void kernel_launch(void* const* d_in, const int* in_sizes, int n_in,
                              void* d_out, int out_size, void* d_ws, size_t ws_size,
                              hipStream_t stream){
    const float* x   = (const float*)d_in[0];
    const float* W0  = (const float*)d_in[1];
    const float* b0  = (const float*)d_in[2];
    const float* W1  = (const float*)d_in[3];
    const float* b1  = (const float*)d_in[4];
    const float* W2  = (const float*)d_in[5];
    const float* b2  = (const float*)d_in[6];
    const float* fcW = (const float*)d_in[7];
    const float* fcb = (const float*)d_in[8];
    float* out = (float*)d_out;

    char* ws = (char*)d_ws;
    unsigned short* Xt  = (unsigned short*)(ws);             // 4 MB
    unsigned short* Wt0 = (unsigned short*)(ws + 4194304);   // 512 KB
    unsigned short* Wt1 = (unsigned short*)(ws + 4718592);   // 2 MB
    unsigned short* Wt2 = (unsigned short*)(ws + 6815744);   // 2 MB
    unsigned short* H0  = (unsigned short*)(ws + 8912896);   // 16 MB
    unsigned short* H1  = (unsigned short*)(ws + 25690112);  // 16 MB (end 42467328)

    prep_wt<<<dim3(16, 4), 256, 0, stream>>>(W0, Wt0, 1024);
    prep_wt<<<dim3(64, 4), 256, 0, stream>>>(W1, Wt1, 4096);
    prep_wt<<<dim3(64, 4), 256, 0, stream>>>(W2, Wt2, 4096);
    prep_x <<<1024, 256, 0, stream>>>(x, Xt);
    init_out<<<4, 256, 0, stream>>>(out, fcb);

    cin_stage< 32, 1024, 128, true ><<<512, 256, 0, stream>>>(Xt, Xt, Wt0, b0, fcW,       H0, out);
    cin_stage<128, 4096, 128, true ><<<512, 256, 0, stream>>>(Xt, H0, Wt1, b1, fcW + 128, H1, out);
    cin_stage<128, 4096, 256, false><<<512, 256, 0, stream>>>(Xt, H1, Wt2, b2, fcW + 256, nullptr, out);
}